// Round 5
// baseline (325.081 us; speedup 1.0000x reference)
//
#include <hip/hip_runtime.h>
#include <stdint.h>

typedef unsigned short u16;
typedef unsigned long long u64;
typedef __bf16 bf16x8 __attribute__((ext_vector_type(8)));
typedef float f32x4 __attribute__((ext_vector_type(4)));
typedef float f32x16 __attribute__((ext_vector_type(16)));
typedef u16 u16x8 __attribute__((ext_vector_type(8)));

// f32 -> bf16 round-to-nearest-even (branchless; inputs finite)
__device__ __forceinline__ u16 f2bf(float x) {
    union { float f; uint32_t u; } c; c.f = x;
    uint32_t r = (c.u + 0x7fffu + ((c.u >> 16) & 1u)) >> 16;
    return (u16)r;
}

// async global->LDS, 16B per lane. LDS dest = wave-uniform base + lane*16.
__device__ __forceinline__ void async16(const void* g, void* l) {
    __builtin_amdgcn_global_load_lds(
        (const __attribute__((address_space(1))) uint32_t*)g,
        (__attribute__((address_space(3))) uint32_t*)l,
        16, 0, 0);
}

// v_permlane32_swap_b32: a' = [a_lo, b_lo(from partner)], b' = [a_hi(from partner), b_hi]
__device__ __forceinline__ void permswap(uint32_t& a, uint32_t& b) {
    asm volatile("v_permlane32_swap_b32 %0, %1" : "+v"(a), "+v"(b));
}

// ---------------- weight transpose + bf16 convert: dst[n][k] = src[k][n] ----
__global__ void transpose_w(const float* __restrict__ src, u16* __restrict__ dst,
                            int K, int N) {
    __shared__ float t[64][65];
    const int nt = N / 64;
    const int k0 = (int)(blockIdx.x / nt) * 64, n0 = (int)(blockIdx.x % nt) * 64;
    const int c = threadIdx.x & 63, r0 = threadIdx.x >> 6;
#pragma unroll
    for (int i = 0; i < 16; ++i) {
        int r = r0 + i * 4;
        t[r][c] = src[(size_t)(k0 + r) * N + n0 + c];
    }
    __syncthreads();
#pragma unroll
    for (int i = 0; i < 16; ++i) {
        int r = r0 + i * 4;
        dst[(size_t)(n0 + r) * K + k0 + c] = f2bf(t[c][r]);
    }
}

// ---------------- V transpose: src [bh][2048][64] -> dst [bh][64][2048] -----
__global__ void transpose_v(const u16* __restrict__ src, u16* __restrict__ dst) {
    __shared__ u16 t[64][66];
    const int bh = blockIdx.x >> 5, kt = blockIdx.x & 31;
    const int tid = threadIdx.x;
    const u16* sp = src + ((size_t)bh * 2048 + kt * 64) * 64;
#pragma unroll
    for (int i = 0; i < 2; ++i) {
        int r = (tid >> 3) + i * 32;
        int c0 = (tid & 7) * 8;
        u16x8 v = *(const u16x8*)(sp + (size_t)r * 64 + c0);
#pragma unroll
        for (int j = 0; j < 8; ++j) t[r][c0 + j] = v[j];
    }
    __syncthreads();
    u16* dp = dst + ((size_t)bh * 64) * 2048 + kt * 64;
#pragma unroll
    for (int i = 0; i < 2; ++i) {
        int d = (tid >> 3) + i * 32;
        int k0 = (tid & 7) * 8;
        u16x8 o;
#pragma unroll
        for (int j = 0; j < 8; ++j) o[j] = t[k0 + j][d];
        *(u16x8*)(dp + (size_t)d * 2048 + k0) = o;
    }
}

// ---------------- adjacency -> bitmask (1 bit per entry) ---------------------
__global__ void pack_adj(const float* __restrict__ adj, u64* __restrict__ bits) {
    const int wid = blockIdx.x * 4 + (threadIdx.x >> 6);
    const int lane = threadIdx.x & 63;
    float v = adj[(size_t)wid * 64 + lane];
    u64 mask = __ballot(v > 0.5f);
    if (lane == 0) bits[wid] = mask;
}

// ---------------- LayerNorm over D=512, one wave per row, bf16 out ----------
__global__ void ln_kernel(const float* __restrict__ x, const float* __restrict__ g,
                          const float* __restrict__ b, u16* __restrict__ out) {
    const int w = threadIdx.x >> 6, lane = threadIdx.x & 63;
    const int row = blockIdx.x * 4 + w;
    const float* xr = x + (size_t)row * 512;
    float4 v0 = *(const float4*)(xr + lane * 8);
    float4 v1 = *(const float4*)(xr + lane * 8 + 4);
    float sum = v0.x + v0.y + v0.z + v0.w + v1.x + v1.y + v1.z + v1.w;
    float sq = v0.x * v0.x + v0.y * v0.y + v0.z * v0.z + v0.w * v0.w +
               v1.x * v1.x + v1.y * v1.y + v1.z * v1.z + v1.w * v1.w;
#pragma unroll
    for (int m = 1; m < 64; m <<= 1) {
        sum += __shfl_xor(sum, m);
        sq  += __shfl_xor(sq, m);
    }
    float mu = sum * (1.f / 512.f);
    float var = sq * (1.f / 512.f) - mu * mu;
    float rs = rsqrtf(var + 1e-5f);
    float4 g0 = *(const float4*)(g + lane * 8), g1 = *(const float4*)(g + lane * 8 + 4);
    float4 b0 = *(const float4*)(b + lane * 8), b1 = *(const float4*)(b + lane * 8 + 4);
    u16x8 o;
    o[0] = f2bf((v0.x - mu) * rs * g0.x + b0.x);
    o[1] = f2bf((v0.y - mu) * rs * g0.y + b0.y);
    o[2] = f2bf((v0.z - mu) * rs * g0.z + b0.z);
    o[3] = f2bf((v0.w - mu) * rs * g0.w + b0.w);
    o[4] = f2bf((v1.x - mu) * rs * g1.x + b1.x);
    o[5] = f2bf((v1.y - mu) * rs * g1.y + b1.y);
    o[6] = f2bf((v1.z - mu) * rs * g1.z + b1.z);
    o[7] = f2bf((v1.w - mu) * rs * g1.w + b1.w);
    *(u16x8*)(out + (size_t)row * 512 + lane * 8) = o;
}

// ---------------- bf16 MFMA GEMM, C = A[M,K] @ Bt[N,K]^T, fused epilogues ---
template <int WM, int WN, int EPI>
__global__ __launch_bounds__(256, 2)
void gemm_bt(const u16* __restrict__ A, const u16* __restrict__ Bt,
             int N, int K,
             const float* __restrict__ b0, const float* __restrict__ b1,
             const float* __restrict__ b2, const float* __restrict__ addf,
             float* __restrict__ outf,
             u16* __restrict__ o0, u16* __restrict__ o1, u16* __restrict__ o2) {
    constexpr int BM = 2 * WM, BN = 2 * WN;
    constexpr int MI = WM / 16, NI = WN / 16;
    constexpr int LA = BM / 32, LB = BN / 32;
    __shared__ __align__(16) u16 Als[BM * 64];
    __shared__ __align__(16) u16 Bls[BN * 64];
    const int tid = threadIdx.x, w = tid >> 6, lane = tid & 63;
    const int nbn = N / BN;
    const int bm0 = (int)(blockIdx.x / nbn) * BM;
    const int bn0 = (int)(blockIdx.x % nbn) * BN;
    const int wr = w >> 1, wc = w & 1;
    const int srow = lane >> 3, schunk = lane & 7;
    f32x4 acc[MI][NI];
#pragma unroll
    for (int i = 0; i < MI; ++i)
#pragma unroll
        for (int j = 0; j < NI; ++j) acc[i][j] = f32x4{0.f, 0.f, 0.f, 0.f};

    for (int k0 = 0; k0 < K; k0 += 64) {
#pragma unroll
        for (int j = 0; j < LA; ++j) {
            int li = w * LA + j;
            int r = li * 8 + srow;
            async16(A + (size_t)(bm0 + r) * K + k0 + ((schunk ^ (r & 7)) << 3), &Als[li * 512]);
        }
#pragma unroll
        for (int j = 0; j < LB; ++j) {
            int li = w * LB + j;
            int r = li * 8 + srow;
            async16(Bt + (size_t)(bn0 + r) * K + k0 + ((schunk ^ (r & 7)) << 3), &Bls[li * 512]);
        }
        __syncthreads();
#pragma unroll
        for (int ks = 0; ks < 2; ++ks) {
            bf16x8 af[MI], bfr[NI];
            const int ck = ks * 4 + (lane >> 4);
#pragma unroll
            for (int mi = 0; mi < MI; ++mi) {
                int r = wr * WM + mi * 16 + (lane & 15);
                af[mi] = *(const bf16x8*)&Als[r * 64 + ((ck ^ (r & 7)) << 3)];
            }
#pragma unroll
            for (int ni = 0; ni < NI; ++ni) {
                int r = wc * WN + ni * 16 + (lane & 15);
                bfr[ni] = *(const bf16x8*)&Bls[r * 64 + ((ck ^ (r & 7)) << 3)];
            }
#pragma unroll
            for (int mi = 0; mi < MI; ++mi)
#pragma unroll
                for (int ni = 0; ni < NI; ++ni)
                    acc[mi][ni] = __builtin_amdgcn_mfma_f32_16x16x32_bf16(
                        af[mi], bfr[ni], acc[mi][ni], 0, 0, 0);
        }
        __syncthreads();
    }
#pragma unroll
    for (int mi = 0; mi < MI; ++mi)
#pragma unroll
        for (int ni = 0; ni < NI; ++ni)
#pragma unroll
            for (int reg = 0; reg < 4; ++reg) {
                int row = bm0 + wr * WM + mi * 16 + ((lane >> 4) << 2) + reg;
                int col = bn0 + wc * WN + ni * 16 + (lane & 15);
                float val = acc[mi][ni][reg];
                if constexpr (EPI == 0) {
                    int wsel = col >> 9, jj = col & 511;
                    const float* bb = wsel == 0 ? b0 : (wsel == 1 ? b1 : b2);
                    u16* dst = wsel == 0 ? o0 : (wsel == 1 ? o1 : o2);
                    val += bb[jj];
                    int h = jj >> 6, hd = jj & 63;
                    int b_ = row >> 11, n_ = row & 2047;
                    dst[(((size_t)(b_ * 8 + h) * 2048 + n_) << 6) + hd] = f2bf(val);
                } else if constexpr (EPI == 1) {
                    val += b0[col] + addf[(size_t)row * 512 + col];
                    outf[(size_t)row * 512 + col] = val;
                } else {
                    float x = val + b0[col];
                    float gx = 0.5f * x * (1.0f + erff(x * 0.70710678118654752f));
                    o0[(size_t)row * 2048 + col] = f2bf(gx);
                }
            }
}

// ---------------- flash attention, swapped-QK^T, barrier-free main loop ----
// grid: blockIdx = qt*32 + bh (bh low bits -> per-bh K/V sticks to one XCD L2)
// block: 4 waves = (qg in {0,1}) x (ks in {0,1}); wave (qg,ks) does q-rows
// [qt*64+qg*32, +32) vs keys [ks*1024, +1024). Fixed-M softmax -> O,L are pure
// sums; cross-ks combine via LDS once at the end. K and V fragments are read
// DIRECTLY from global (L2-resident; vT pre-transposed so V-frags are 16B
// contiguous per lane). Zero barriers / zero LDS in the main loop.
__global__ __launch_bounds__(256, 4)
void attn32_kernel(const u16* __restrict__ q, const u16* __restrict__ k,
                   const u16* __restrict__ vT, const u64* __restrict__ adjbits,
                   u16* __restrict__ att) {
    const int tid = threadIdx.x, w = tid >> 6;
    const int lane = tid & 63, col = lane & 31, g = lane >> 5;
    const int qg = w >> 1, ks = w & 1;
    const int bh = blockIdx.x & 31, qt = blockIdx.x >> 5;
    const int b_ = bh >> 3, h_ = bh & 7;
    __shared__ float Obuf[2][32][64];   // ks=1 partial O
    __shared__ float Lls[2][2][32];     // [qg][ks][q]
    const int q0 = qt * 64 + qg * 32;
    const int myq = q0 + col;
    const u16* qptr = q + ((size_t)bh * 2048 + myq) * 64 + g * 8;
    const u16* kptr = k + ((size_t)bh * 2048 + ks * 1024 + col) * 64 + g * 8;
    const u16* vptrA = vT + ((size_t)bh * 64 + col) * 2048 + ks * 1024 + g * 8;
    const u16* vptrB = vptrA + (size_t)32 * 2048;
    const u64* adjrow = adjbits + ((size_t)b_ * 2048 + myq) * 32 + ks * 16;

    bf16x8 Qf[4];
#pragma unroll
    for (int c = 0; c < 4; ++c) Qf[c] = *(const bf16x8*)(qptr + c * 16);
    f32x16 O0, O1;
#pragma unroll
    for (int i = 0; i < 16; ++i) { O0[i] = 0.f; O1[i] = 0.f; }
    float L = 0.f;

    for (int it = 0; it < 16; ++it) {
        const u64 adjw = adjrow[it];
#pragma unroll
        for (int s = 0; s < 2; ++s) {
            const int kv = it * 64 + s * 32;
            bf16x8 Ku[4];
#pragma unroll
            for (int c = 0; c < 4; ++c)
                Ku[c] = *(const bf16x8*)(kptr + (size_t)kv * 64 + c * 16);
            // V-frags for this 32-key half: issued before QK^T so the softmax
            // VALU stretch hides their L2 latency.
            bf16x8 fvA[2], fvB[2];
#pragma unroll
            for (int c2 = 0; c2 < 2; ++c2) {
                fvA[c2] = *(const bf16x8*)(vptrA + kv + c2 * 16);
                fvB[c2] = *(const bf16x8*)(vptrB + kv + c2 * 16);
            }
            f32x16 S;
#pragma unroll
            for (int i = 0; i < 16; ++i) S[i] = 0.f;
            __builtin_amdgcn_s_setprio(1);
#pragma unroll
            for (int c = 0; c < 4; ++c)
                S = __builtin_amdgcn_mfma_f32_32x32x16_bf16(Ku[c], Qf[c], S, 0, 0, 0);
            __builtin_amdgcn_s_setprio(0);
            uint32_t w32 = (uint32_t)(adjw >> (32 * s));
            // P = exp2(S*log2e/8 + cst(edge)); fixed offset M=12 (no online max:
            // masked logits bounded; uniform M cancels exactly in O/L)
            float p[16];
#pragma unroll
            for (int r_ = 0; r_ < 16; ++r_) {
                int bit = (r_ & 3) + 8 * (r_ >> 2) + 4 * g;
                float cst = ((w32 >> bit) & 1u) ? -15.8696454f : -20.7550354f;
                p[r_] = __builtin_amdgcn_exp2f(S[r_] * 0.18033688f + cst);
            }
            float t0 = (p[0] + p[1]) + (p[2] + p[3]);
            float t1 = (p[4] + p[5]) + (p[6] + p[7]);
            float t2s = (p[8] + p[9]) + (p[10] + p[11]);
            float t3 = (p[12] + p[13]) + (p[14] + p[15]);
            L += (t0 + t1) + (t2s + t3);
            // pack to bf16 + permlane redistribution -> PV A-fragments
            uint32_t pk[8];
#pragma unroll
            for (int i = 0; i < 8; ++i) {
                union { __bf16 h[2]; uint32_t u; } pu;
                pu.h[0] = (__bf16)p[2 * i]; pu.h[1] = (__bf16)p[2 * i + 1];
                pk[i] = pu.u;
            }
            permswap(pk[0], pk[2]); permswap(pk[1], pk[3]);
            permswap(pk[4], pk[6]); permswap(pk[5], pk[7]);
            union { uint32_t u[4]; bf16x8 v; } fa0, fa1;
            fa0.u[0] = pk[0]; fa0.u[1] = pk[1]; fa0.u[2] = pk[2]; fa0.u[3] = pk[3];
            fa1.u[0] = pk[4]; fa1.u[1] = pk[5]; fa1.u[2] = pk[6]; fa1.u[3] = pk[7];
            __builtin_amdgcn_s_setprio(1);
            O0 = __builtin_amdgcn_mfma_f32_32x32x16_bf16(fa0.v, fvA[0], O0, 0, 0, 0);
            O1 = __builtin_amdgcn_mfma_f32_32x32x16_bf16(fa0.v, fvB[0], O1, 0, 0, 0);
            O0 = __builtin_amdgcn_mfma_f32_32x32x16_bf16(fa1.v, fvA[1], O0, 0, 0, 0);
            O1 = __builtin_amdgcn_mfma_f32_32x32x16_bf16(fa1.v, fvB[1], O1, 0, 0, 0);
            __builtin_amdgcn_s_setprio(0);
        }
    }

    // cross-g L merge (per q-col), publish per-(qg,ks) L
    float Lt = L + __shfl_xor(L, 32);
    if (g == 0) Lls[qg][ks][col] = Lt;
    __syncthreads();
    // ks=1 publishes O into LDS, ks=0 combines + writes out
    if (ks == 1) {
#pragma unroll
        for (int r_ = 0; r_ < 16; ++r_) {
            int qrow = (r_ & 3) + 8 * (r_ >> 2) + 4 * g;
            Obuf[qg][qrow][col] = O0[r_];
            Obuf[qg][qrow][32 + col] = O1[r_];
        }
    }
    __syncthreads();
    if (ks == 0) {
        u16* outp = att + ((size_t)b_ * 2048 + q0) * 512 + (h_ << 6);
#pragma unroll
        for (int r_ = 0; r_ < 16; ++r_) {
            int qrow = (r_ & 3) + 8 * (r_ >> 2) + 4 * g;
            float lsum = Lls[qg][0][qrow] + Lls[qg][1][qrow];
            float inv = __builtin_amdgcn_rcpf(lsum);
            float o0 = O0[r_] + Obuf[qg][qrow][col];
            float o1 = O1[r_] + Obuf[qg][qrow][32 + col];
            outp[(size_t)qrow * 512 + col] = f2bf(o0 * inv);
            outp[(size_t)qrow * 512 + 32 + col] = f2bf(o1 * inv);
        }
    }
}

// ---------------------------------------------------------------------------
extern "C" void kernel_launch(void* const* d_in, const int* in_sizes, int n_in,
                              void* d_out, int out_size, void* d_ws, size_t ws_size,
                              hipStream_t stream) {
    const float* hidden = (const float*)d_in[0];
    const float* adj    = (const float*)d_in[1];
    const float* Wq = (const float*)d_in[2];
    const float* bq = (const float*)d_in[3];
    const float* Wk = (const float*)d_in[4];
    const float* bk = (const float*)d_in[5];
    const float* Wv = (const float*)d_in[6];
    const float* bv = (const float*)d_in[7];
    const float* Wo = (const float*)d_in[8];
    const float* bo = (const float*)d_in[9];
    const float* g1 = (const float*)d_in[10];
    const float* b1 = (const float*)d_in[11];
    const float* g2 = (const float*)d_in[12];
    const float* b2 = (const float*)d_in[13];
    const float* Wf1 = (const float*)d_in[14];
    const float* bf1 = (const float*)d_in[15];
    const float* Wf2 = (const float*)d_in[16];
    const float* bf2 = (const float*)d_in[17];
    float* out = (float*)d_out;

    char* p = (char*)d_ws;
    u16* wqkv_t = (u16*)p; p += (size_t)1536 * 512 * 2;
    u16* wo_t   = (u16*)p; p += (size_t)512 * 512 * 2;
    u16* wf1_t  = (u16*)p; p += (size_t)2048 * 512 * 2;
    u16* wf2_t  = (u16*)p; p += (size_t)512 * 2048 * 2;
    u64* adjbits = (u64*)p; p += (size_t)4 * 2048 * 32 * 8;
    u16* bufA = (u16*)p; p += (size_t)8192 * 512 * 2;   // normed, then attended
    u16* bufQ = (u16*)p; p += (size_t)8192 * 512 * 2;   // q, then h2
    float* mid = (float*)p; p += (size_t)8192 * 512 * 4;
    u16* kbuf = (u16*)p; p += (size_t)8192 * 512 * 2;
    u16* vbuf = (u16*)p; p += (size_t)8192 * 512 * 2;
    p += (size_t)16 * 1024 * 1024;                       // ffh tail
    u16* ffh = kbuf;  // 8192*2048 bf16 spans kbuf+vbuf+tail (dead after attention)
    u16* vT = (u16*)mid;  // [32 bh][64 hd][2048 key] bf16; mid is dead until Wo-GEMM
    (void)ws_size; (void)in_sizes; (void)n_in; (void)out_size;

    transpose_w<<<64, 256, 0, stream>>>(Wq, wqkv_t, 512, 512);
    transpose_w<<<64, 256, 0, stream>>>(Wk, wqkv_t + (size_t)512 * 512, 512, 512);
    transpose_w<<<64, 256, 0, stream>>>(Wv, wqkv_t + (size_t)1024 * 512, 512, 512);
    transpose_w<<<64, 256, 0, stream>>>(Wo, wo_t, 512, 512);
    transpose_w<<<256, 256, 0, stream>>>(Wf1, wf1_t, 512, 2048);
    transpose_w<<<256, 256, 0, stream>>>(Wf2, wf2_t, 2048, 512);
    pack_adj<<<65536, 256, 0, stream>>>(adj, adjbits);
    ln_kernel<<<2048, 256, 0, stream>>>(hidden, g1, b1, bufA);
    gemm_bt<64, 64, 0><<<64 * 12, 256, 0, stream>>>(bufA, wqkv_t, 1536, 512,
        bq, bk, bv, nullptr, nullptr, bufQ, kbuf, vbuf);
    transpose_v<<<1024, 256, 0, stream>>>(vbuf, vT);
    attn32_kernel<<<1024, 256, 0, stream>>>(bufQ, kbuf, vT, adjbits, bufA);
    gemm_bt<32, 32, 1><<<128 * 8, 256, 0, stream>>>(bufA, wo_t, 512, 512,
        bo, nullptr, nullptr, hidden, mid, nullptr, nullptr, nullptr);
    ln_kernel<<<2048, 256, 0, stream>>>(mid, g2, b2, bufQ);
    gemm_bt<64, 64, 2><<<64 * 16, 256, 0, stream>>>(bufQ, wf1_t, 2048, 512,
        bf1, nullptr, nullptr, nullptr, nullptr, ffh, nullptr, nullptr);
    gemm_bt<32, 32, 1><<<128 * 8, 256, 0, stream>>>(ffh, wf2_t, 512, 2048,
        bf2, nullptr, nullptr, mid, out, nullptr, nullptr, nullptr);
}

// Round 6
// 265.823 us; speedup vs baseline: 1.2229x; 1.2229x over previous
//
#include <hip/hip_runtime.h>
#include <stdint.h>

typedef unsigned short u16;
typedef unsigned long long u64;
typedef __bf16 bf16x8 __attribute__((ext_vector_type(8)));
typedef float f32x4 __attribute__((ext_vector_type(4)));
typedef float f32x16 __attribute__((ext_vector_type(16)));
typedef u16 u16x8 __attribute__((ext_vector_type(8)));

// f32 -> bf16 round-to-nearest-even (branchless; inputs finite)
__device__ __forceinline__ u16 f2bf(float x) {
    union { float f; uint32_t u; } c; c.f = x;
    uint32_t r = (c.u + 0x7fffu + ((c.u >> 16) & 1u)) >> 16;
    return (u16)r;
}

// async global->LDS, 16B per lane. LDS dest = wave-uniform base + lane*16.
__device__ __forceinline__ void async16(const void* g, void* l) {
    __builtin_amdgcn_global_load_lds(
        (const __attribute__((address_space(1))) uint32_t*)g,
        (__attribute__((address_space(3))) uint32_t*)l,
        16, 0, 0);
}

// v_permlane32_swap_b32: a' = [a_lo, b_lo(from partner)], b' = [a_hi(from partner), b_hi]
__device__ __forceinline__ void permswap(uint32_t& a, uint32_t& b) {
    asm volatile("v_permlane32_swap_b32 %0, %1" : "+v"(a), "+v"(b));
}

// ---------------- weight transpose + bf16 convert: dst[n][k] = src[k][n] ----
__global__ void transpose_w(const float* __restrict__ src, u16* __restrict__ dst,
                            int K, int N) {
    __shared__ float t[64][65];
    const int nt = N / 64;
    const int k0 = (int)(blockIdx.x / nt) * 64, n0 = (int)(blockIdx.x % nt) * 64;
    const int c = threadIdx.x & 63, r0 = threadIdx.x >> 6;
#pragma unroll
    for (int i = 0; i < 16; ++i) {
        int r = r0 + i * 4;
        t[r][c] = src[(size_t)(k0 + r) * N + n0 + c];
    }
    __syncthreads();
#pragma unroll
    for (int i = 0; i < 16; ++i) {
        int r = r0 + i * 4;
        dst[(size_t)(n0 + r) * K + k0 + c] = f2bf(t[c][r]);
    }
}

// ---------------- V transpose: src [bh][2048][64] -> dst [bh][64][2048] -----
__global__ void transpose_v(const u16* __restrict__ src, u16* __restrict__ dst) {
    __shared__ u16 t[64][66];
    const int bh = blockIdx.x >> 5, kt = blockIdx.x & 31;
    const int tid = threadIdx.x;
    const u16* sp = src + ((size_t)bh * 2048 + kt * 64) * 64;
#pragma unroll
    for (int i = 0; i < 2; ++i) {
        int r = (tid >> 3) + i * 32;
        int c0 = (tid & 7) * 8;
        u16x8 v = *(const u16x8*)(sp + (size_t)r * 64 + c0);
#pragma unroll
        for (int j = 0; j < 8; ++j) t[r][c0 + j] = v[j];
    }
    __syncthreads();
    u16* dp = dst + ((size_t)bh * 64) * 2048 + kt * 64;
#pragma unroll
    for (int i = 0; i < 2; ++i) {
        int d = (tid >> 3) + i * 32;
        int k0 = (tid & 7) * 8;
        u16x8 o;
#pragma unroll
        for (int j = 0; j < 8; ++j) o[j] = t[k0 + j][d];
        *(u16x8*)(dp + (size_t)d * 2048 + k0) = o;
    }
}

// ---------------- adjacency -> bitmask (1 bit per entry) ---------------------
__global__ void pack_adj(const float* __restrict__ adj, u64* __restrict__ bits) {
    const int wid = blockIdx.x * 4 + (threadIdx.x >> 6);
    const int lane = threadIdx.x & 63;
    float v = adj[(size_t)wid * 64 + lane];
    u64 mask = __ballot(v > 0.5f);
    if (lane == 0) bits[wid] = mask;
}

// ---------------- LayerNorm over D=512, one wave per row, bf16 out ----------
__global__ void ln_kernel(const float* __restrict__ x, const float* __restrict__ g,
                          const float* __restrict__ b, u16* __restrict__ out) {
    const int w = threadIdx.x >> 6, lane = threadIdx.x & 63;
    const int row = blockIdx.x * 4 + w;
    const float* xr = x + (size_t)row * 512;
    float4 v0 = *(const float4*)(xr + lane * 8);
    float4 v1 = *(const float4*)(xr + lane * 8 + 4);
    float sum = v0.x + v0.y + v0.z + v0.w + v1.x + v1.y + v1.z + v1.w;
    float sq = v0.x * v0.x + v0.y * v0.y + v0.z * v0.z + v0.w * v0.w +
               v1.x * v1.x + v1.y * v1.y + v1.z * v1.z + v1.w * v1.w;
#pragma unroll
    for (int m = 1; m < 64; m <<= 1) {
        sum += __shfl_xor(sum, m);
        sq  += __shfl_xor(sq, m);
    }
    float mu = sum * (1.f / 512.f);
    float var = sq * (1.f / 512.f) - mu * mu;
    float rs = rsqrtf(var + 1e-5f);
    float4 g0 = *(const float4*)(g + lane * 8), g1 = *(const float4*)(g + lane * 8 + 4);
    float4 b0 = *(const float4*)(b + lane * 8), b1 = *(const float4*)(b + lane * 8 + 4);
    u16x8 o;
    o[0] = f2bf((v0.x - mu) * rs * g0.x + b0.x);
    o[1] = f2bf((v0.y - mu) * rs * g0.y + b0.y);
    o[2] = f2bf((v0.z - mu) * rs * g0.z + b0.z);
    o[3] = f2bf((v0.w - mu) * rs * g0.w + b0.w);
    o[4] = f2bf((v1.x - mu) * rs * g1.x + b1.x);
    o[5] = f2bf((v1.y - mu) * rs * g1.y + b1.y);
    o[6] = f2bf((v1.z - mu) * rs * g1.z + b1.z);
    o[7] = f2bf((v1.w - mu) * rs * g1.w + b1.w);
    *(u16x8*)(out + (size_t)row * 512 + lane * 8) = o;
}

// ---------------- bf16 MFMA GEMM, C = A[M,K] @ Bt[N,K]^T, fused epilogues ---
template <int WM, int WN, int EPI>
__global__ __launch_bounds__(256, 2)
void gemm_bt(const u16* __restrict__ A, const u16* __restrict__ Bt,
             int N, int K,
             const float* __restrict__ b0, const float* __restrict__ b1,
             const float* __restrict__ b2, const float* __restrict__ addf,
             float* __restrict__ outf,
             u16* __restrict__ o0, u16* __restrict__ o1, u16* __restrict__ o2) {
    constexpr int BM = 2 * WM, BN = 2 * WN;
    constexpr int MI = WM / 16, NI = WN / 16;
    constexpr int LA = BM / 32, LB = BN / 32;
    __shared__ __align__(16) u16 Als[BM * 64];
    __shared__ __align__(16) u16 Bls[BN * 64];
    const int tid = threadIdx.x, w = tid >> 6, lane = tid & 63;
    const int nbn = N / BN;
    const int bm0 = (int)(blockIdx.x / nbn) * BM;
    const int bn0 = (int)(blockIdx.x % nbn) * BN;
    const int wr = w >> 1, wc = w & 1;
    const int srow = lane >> 3, schunk = lane & 7;
    f32x4 acc[MI][NI];
#pragma unroll
    for (int i = 0; i < MI; ++i)
#pragma unroll
        for (int j = 0; j < NI; ++j) acc[i][j] = f32x4{0.f, 0.f, 0.f, 0.f};

    for (int k0 = 0; k0 < K; k0 += 64) {
#pragma unroll
        for (int j = 0; j < LA; ++j) {
            int li = w * LA + j;
            int r = li * 8 + srow;
            async16(A + (size_t)(bm0 + r) * K + k0 + ((schunk ^ (r & 7)) << 3), &Als[li * 512]);
        }
#pragma unroll
        for (int j = 0; j < LB; ++j) {
            int li = w * LB + j;
            int r = li * 8 + srow;
            async16(Bt + (size_t)(bn0 + r) * K + k0 + ((schunk ^ (r & 7)) << 3), &Bls[li * 512]);
        }
        __syncthreads();
#pragma unroll
        for (int ks = 0; ks < 2; ++ks) {
            bf16x8 af[MI], bfr[NI];
            const int ck = ks * 4 + (lane >> 4);
#pragma unroll
            for (int mi = 0; mi < MI; ++mi) {
                int r = wr * WM + mi * 16 + (lane & 15);
                af[mi] = *(const bf16x8*)&Als[r * 64 + ((ck ^ (r & 7)) << 3)];
            }
#pragma unroll
            for (int ni = 0; ni < NI; ++ni) {
                int r = wc * WN + ni * 16 + (lane & 15);
                bfr[ni] = *(const bf16x8*)&Bls[r * 64 + ((ck ^ (r & 7)) << 3)];
            }
#pragma unroll
            for (int mi = 0; mi < MI; ++mi)
#pragma unroll
                for (int ni = 0; ni < NI; ++ni)
                    acc[mi][ni] = __builtin_amdgcn_mfma_f32_16x16x32_bf16(
                        af[mi], bfr[ni], acc[mi][ni], 0, 0, 0);
        }
        __syncthreads();
    }
#pragma unroll
    for (int mi = 0; mi < MI; ++mi)
#pragma unroll
        for (int ni = 0; ni < NI; ++ni)
#pragma unroll
            for (int reg = 0; reg < 4; ++reg) {
                int row = bm0 + wr * WM + mi * 16 + ((lane >> 4) << 2) + reg;
                int col = bn0 + wc * WN + ni * 16 + (lane & 15);
                float val = acc[mi][ni][reg];
                if constexpr (EPI == 0) {
                    int wsel = col >> 9, jj = col & 511;
                    const float* bb = wsel == 0 ? b0 : (wsel == 1 ? b1 : b2);
                    u16* dst = wsel == 0 ? o0 : (wsel == 1 ? o1 : o2);
                    val += bb[jj];
                    int h = jj >> 6, hd = jj & 63;
                    int b_ = row >> 11, n_ = row & 2047;
                    dst[(((size_t)(b_ * 8 + h) * 2048 + n_) << 6) + hd] = f2bf(val);
                } else if constexpr (EPI == 1) {
                    val += b0[col] + addf[(size_t)row * 512 + col];
                    outf[(size_t)row * 512 + col] = val;
                } else {
                    float x = val + b0[col];
                    float gx = 0.5f * x * (1.0f + erff(x * 0.70710678118654752f));
                    o0[(size_t)row * 2048 + col] = f2bf(gx);
                }
            }
}

// ---------------- flash attention, swapped-QK^T, split-K over waves ---------
// grid: blockIdx = qt*32 + bh  (bh low bits -> per-bh K/V sticks to one XCD L2)
// block: 4 waves = (qg in {0,1}) x (ks in {0,1}); wave (qg,ks) does q-rows
// [qt*64+qg*32, +32) against keys [ks*1024, +1024). Fixed-M softmax -> O,L are
// pure sums; cross-ks combine is exact addition via LDS at the end.
// V is pre-transposed (vT[bh][hd][key]) and staged via global_load_lds with
// the XOR swizzle folded into the global source address (LDS dest linear).
// NOTE __launch_bounds__(256,3): live set ~140 VGPR; a 128-reg cap (4/EU)
// spills to scratch (R3/R5: WRITE_SIZE 40-600MB) and spill >> occupancy gain.
__global__ __launch_bounds__(256, 3)
void attn32_kernel(const u16* __restrict__ q, const u16* __restrict__ k,
                   const u16* __restrict__ vT, const u64* __restrict__ adjbits,
                   u16* __restrict__ att) {
    const int tid = threadIdx.x, w = tid >> 6;
    const int lane = tid & 63, col = lane & 31, g = lane >> 5;
    const int qg = w >> 1, ks = w & 1;
    const int bh = blockIdx.x & 31, qt = blockIdx.x >> 5;
    const int b_ = bh >> 3, h_ = bh & 7;
    __shared__ __align__(16) u16 Vt[2][2][4096];   // [ks][buf][64 hd x 64 key], swizzled
    __shared__ float Lls[2][2][32];                // [qg][ks][q]
    const int q0 = qt * 64 + qg * 32;
    const int myq = q0 + col;
    const u16* qptr = q + ((size_t)bh * 2048 + myq) * 64 + g * 8;
    const u16* kptr = k + ((size_t)bh * 2048 + ks * 1024 + col) * 64 + g * 8;
    const u64* adjrow = adjbits + ((size_t)b_ * 2048 + myq) * 32 + ks * 16;
    // staging source: lane covers row r = qg*32 + j*8 + (lane>>3), chunk c = lane&7
    const int sr = (lane >> 3), sc = lane & 7;
    const u16* vstage = vT + ((size_t)bh * 64 + qg * 32 + sr) * 2048 + ks * 1024 +
                        (((sc ^ (sr & 7))) << 3);

    bf16x8 Qf[4];
#pragma unroll
    for (int c = 0; c < 4; ++c) Qf[c] = *(const bf16x8*)(qptr + c * 16);
    f32x16 O0, O1;
#pragma unroll
    for (int i = 0; i < 16; ++i) { O0[i] = 0.f; O1[i] = 0.f; }
    float L = 0.f;

    auto stage = [&](int it, int buf) {
#pragma unroll
        for (int j = 0; j < 4; ++j)
            async16(vstage + (size_t)j * 8 * 2048 + it * 64,
                    &Vt[ks][buf][(qg * 4 + j) * 512]);
    };
    stage(0, 0);
    __syncthreads();

    for (int it = 0; it < 16; ++it) {
        const int cur = it & 1;
        if (it < 15) stage(it + 1, cur ^ 1);
        const u64 adjw = adjrow[it];
        const char* vt = (const char*)&Vt[ks][cur][0];
#pragma unroll
        for (int s = 0; s < 2; ++s) {
            bf16x8 Ku[4];
#pragma unroll
            for (int c = 0; c < 4; ++c)
                Ku[c] = *(const bf16x8*)(kptr + (size_t)(it * 64 + s * 32) * 64 + c * 16);
            f32x16 S;
#pragma unroll
            for (int i = 0; i < 16; ++i) S[i] = 0.f;
            __builtin_amdgcn_s_setprio(1);
#pragma unroll
            for (int c = 0; c < 4; ++c)
                S = __builtin_amdgcn_mfma_f32_32x32x16_bf16(Ku[c], Qf[c], S, 0, 0, 0);
            __builtin_amdgcn_s_setprio(0);
            uint32_t w32 = (uint32_t)(adjw >> (32 * s));
            // P = exp2(S*log2e/8 + cst(edge)); fixed offset M=12 (no online max:
            // masked logits bounded; uniform M cancels exactly in O/L)
            float p[16];
#pragma unroll
            for (int r_ = 0; r_ < 16; ++r_) {
                int bit = (r_ & 3) + 8 * (r_ >> 2) + 4 * g;
                float cst = ((w32 >> bit) & 1u) ? -15.8696454f : -20.7550354f;
                p[r_] = __builtin_amdgcn_exp2f(S[r_] * 0.18033688f + cst);
            }
            float t0 = (p[0] + p[1]) + (p[2] + p[3]);
            float t1 = (p[4] + p[5]) + (p[6] + p[7]);
            float t2s = (p[8] + p[9]) + (p[10] + p[11]);
            float t3 = (p[12] + p[13]) + (p[14] + p[15]);
            L += (t0 + t1) + (t2s + t3);
            // pack to bf16 + permlane redistribution -> PV A-fragments
            uint32_t pk[8];
#pragma unroll
            for (int i = 0; i < 8; ++i) {
                union { __bf16 h[2]; uint32_t u; } pu;
                pu.h[0] = (__bf16)p[2 * i]; pu.h[1] = (__bf16)p[2 * i + 1];
                pk[i] = pu.u;
            }
            permswap(pk[0], pk[2]); permswap(pk[1], pk[3]);
            permswap(pk[4], pk[6]); permswap(pk[5], pk[7]);
            union { uint32_t u[4]; bf16x8 v; } fa0, fa1;
            fa0.u[0] = pk[0]; fa0.u[1] = pk[1]; fa0.u[2] = pk[2]; fa0.u[3] = pk[3];
            fa1.u[0] = pk[4]; fa1.u[1] = pk[5]; fa1.u[2] = pk[6]; fa1.u[3] = pk[7];
            __builtin_amdgcn_s_setprio(1);
#pragma unroll
            for (int c2 = 0; c2 < 2; ++c2) {
                int kb = (s * 32 + c2 * 16 + g * 8) * 2;
                int r0 = col, r1 = 32 + col;
                bf16x8 fv0 = *(const bf16x8*)(vt + ((r0 * 128 + kb) ^ ((r0 & 7) << 4)));
                bf16x8 fv1 = *(const bf16x8*)(vt + ((r1 * 128 + kb) ^ ((r1 & 7) << 4)));
                const bf16x8 fa = c2 ? fa1.v : fa0.v;
                O0 = __builtin_amdgcn_mfma_f32_32x32x16_bf16(fa, fv0, O0, 0, 0, 0);
                O1 = __builtin_amdgcn_mfma_f32_32x32x16_bf16(fa, fv1, O1, 0, 0, 0);
            }
            __builtin_amdgcn_s_setprio(0);
        }
        __syncthreads();
    }

    // cross-g L merge (per q-col), publish per-(qg,ks) L
    float Lt = L + __shfl_xor(L, 32);
    if (g == 0) Lls[qg][ks][col] = Lt;
    __syncthreads();
    // ks=1 publishes O into LDS (reuses Vt space), ks=0 combines + writes out
    float* Obuf = (float*)&Vt[0][0][0];  // [2 qg][32 q][64 hd]
    if (ks == 1) {
#pragma unroll
        for (int r_ = 0; r_ < 16; ++r_) {
            int qrow = (r_ & 3) + 8 * (r_ >> 2) + 4 * g;
            Obuf[((qg * 32 + qrow) << 6) + col] = O0[r_];
            Obuf[((qg * 32 + qrow) << 6) + 32 + col] = O1[r_];
        }
    }
    __syncthreads();
    if (ks == 0) {
        u16* outp = att + ((size_t)b_ * 2048 + q0) * 512 + (h_ << 6);
#pragma unroll
        for (int r_ = 0; r_ < 16; ++r_) {
            int qrow = (r_ & 3) + 8 * (r_ >> 2) + 4 * g;
            float lsum = Lls[qg][0][qrow] + Lls[qg][1][qrow];
            float inv = __builtin_amdgcn_rcpf(lsum);
            float o0 = O0[r_] + Obuf[((qg * 32 + qrow) << 6) + col];
            float o1 = O1[r_] + Obuf[((qg * 32 + qrow) << 6) + 32 + col];
            outp[(size_t)qrow * 512 + col] = f2bf(o0 * inv);
            outp[(size_t)qrow * 512 + 32 + col] = f2bf(o1 * inv);
        }
    }
}

// ---------------------------------------------------------------------------
extern "C" void kernel_launch(void* const* d_in, const int* in_sizes, int n_in,
                              void* d_out, int out_size, void* d_ws, size_t ws_size,
                              hipStream_t stream) {
    const float* hidden = (const float*)d_in[0];
    const float* adj    = (const float*)d_in[1];
    const float* Wq = (const float*)d_in[2];
    const float* bq = (const float*)d_in[3];
    const float* Wk = (const float*)d_in[4];
    const float* bk = (const float*)d_in[5];
    const float* Wv = (const float*)d_in[6];
    const float* bv = (const float*)d_in[7];
    const float* Wo = (const float*)d_in[8];
    const float* bo = (const float*)d_in[9];
    const float* g1 = (const float*)d_in[10];
    const float* b1 = (const float*)d_in[11];
    const float* g2 = (const float*)d_in[12];
    const float* b2 = (const float*)d_in[13];
    const float* Wf1 = (const float*)d_in[14];
    const float* bf1 = (const float*)d_in[15];
    const float* Wf2 = (const float*)d_in[16];
    const float* bf2 = (const float*)d_in[17];
    float* out = (float*)d_out;

    char* p = (char*)d_ws;
    u16* wqkv_t = (u16*)p; p += (size_t)1536 * 512 * 2;
    u16* wo_t   = (u16*)p; p += (size_t)512 * 512 * 2;
    u16* wf1_t  = (u16*)p; p += (size_t)2048 * 512 * 2;
    u16* wf2_t  = (u16*)p; p += (size_t)512 * 2048 * 2;
    u64* adjbits = (u64*)p; p += (size_t)4 * 2048 * 32 * 8;
    u16* bufA = (u16*)p; p += (size_t)8192 * 512 * 2;   // normed, then attended
    u16* bufQ = (u16*)p; p += (size_t)8192 * 512 * 2;   // q, then h2
    float* mid = (float*)p; p += (size_t)8192 * 512 * 4;
    u16* kbuf = (u16*)p; p += (size_t)8192 * 512 * 2;
    u16* vbuf = (u16*)p; p += (size_t)8192 * 512 * 2;
    p += (size_t)16 * 1024 * 1024;                       // ffh tail
    u16* ffh = kbuf;  // 8192*2048 bf16 spans kbuf+vbuf+tail (dead after attention)
    u16* vT = (u16*)mid;  // [32 bh][64 hd][2048 key] bf16; mid is dead until Wo-GEMM
    (void)ws_size; (void)in_sizes; (void)n_in; (void)out_size;

    transpose_w<<<64, 256, 0, stream>>>(Wq, wqkv_t, 512, 512);
    transpose_w<<<64, 256, 0, stream>>>(Wk, wqkv_t + (size_t)512 * 512, 512, 512);
    transpose_w<<<64, 256, 0, stream>>>(Wv, wqkv_t + (size_t)1024 * 512, 512, 512);
    transpose_w<<<64, 256, 0, stream>>>(Wo, wo_t, 512, 512);
    transpose_w<<<256, 256, 0, stream>>>(Wf1, wf1_t, 512, 2048);
    transpose_w<<<256, 256, 0, stream>>>(Wf2, wf2_t, 2048, 512);
    pack_adj<<<65536, 256, 0, stream>>>(adj, adjbits);
    ln_kernel<<<2048, 256, 0, stream>>>(hidden, g1, b1, bufA);
    gemm_bt<64, 64, 0><<<64 * 12, 256, 0, stream>>>(bufA, wqkv_t, 1536, 512,
        bq, bk, bv, nullptr, nullptr, bufQ, kbuf, vbuf);
    transpose_v<<<1024, 256, 0, stream>>>(vbuf, vT);
    attn32_kernel<<<1024, 256, 0, stream>>>(bufQ, kbuf, vT, adjbits, bufA);
    gemm_bt<32, 32, 1><<<128 * 8, 256, 0, stream>>>(bufA, wo_t, 512, 512,
        bo, nullptr, nullptr, hidden, mid, nullptr, nullptr, nullptr);
    ln_kernel<<<2048, 256, 0, stream>>>(mid, g2, b2, bufQ);
    gemm_bt<64, 64, 2><<<64 * 16, 256, 0, stream>>>(bufQ, wf1_t, 2048, 512,
        bf1, nullptr, nullptr, nullptr, nullptr, ffh, nullptr, nullptr);
    gemm_bt<32, 32, 1><<<128 * 8, 256, 0, stream>>>(ffh, wf2_t, 512, 2048,
        bf2, nullptr, nullptr, mid, out, nullptr, nullptr, nullptr);
}

// Round 7
// 245.836 us; speedup vs baseline: 1.3223x; 1.0813x over previous
//
#include <hip/hip_runtime.h>
#include <stdint.h>

typedef unsigned short u16;
typedef unsigned long long u64;
typedef __bf16 bf16x8 __attribute__((ext_vector_type(8)));
typedef float f32x4 __attribute__((ext_vector_type(4)));
typedef float f32x16 __attribute__((ext_vector_type(16)));
typedef u16 u16x8 __attribute__((ext_vector_type(8)));

// f32 -> bf16 round-to-nearest-even (branchless; inputs finite)
__device__ __forceinline__ u16 f2bf(float x) {
    union { float f; uint32_t u; } c; c.f = x;
    uint32_t r = (c.u + 0x7fffu + ((c.u >> 16) & 1u)) >> 16;
    return (u16)r;
}

// async global->LDS, 16B per lane. LDS dest = wave-uniform base + lane*16.
__device__ __forceinline__ void async16(const void* g, void* l) {
    __builtin_amdgcn_global_load_lds(
        (const __attribute__((address_space(1))) uint32_t*)g,
        (__attribute__((address_space(3))) uint32_t*)l,
        16, 0, 0);
}

// v_permlane32_swap_b32: a' = [a_lo, b_lo(from partner)], b' = [a_hi(from partner), b_hi]
__device__ __forceinline__ void permswap(uint32_t& a, uint32_t& b) {
    asm volatile("v_permlane32_swap_b32 %0, %1" : "+v"(a), "+v"(b));
}

// ---------------- weight transpose + bf16 convert: dst[n][k] = src[k][n] ----
__global__ void transpose_w(const float* __restrict__ src, u16* __restrict__ dst,
                            int K, int N) {
    __shared__ float t[64][65];
    const int nt = N / 64;
    const int k0 = (int)(blockIdx.x / nt) * 64, n0 = (int)(blockIdx.x % nt) * 64;
    const int c = threadIdx.x & 63, r0 = threadIdx.x >> 6;
#pragma unroll
    for (int i = 0; i < 16; ++i) {
        int r = r0 + i * 4;
        t[r][c] = src[(size_t)(k0 + r) * N + n0 + c];
    }
    __syncthreads();
#pragma unroll
    for (int i = 0; i < 16; ++i) {
        int r = r0 + i * 4;
        dst[(size_t)(n0 + r) * K + k0 + c] = f2bf(t[c][r]);
    }
}

// ---------------- V transpose: src [bh][2048][64] -> dst [bh][64][2048] -----
__global__ void transpose_v(const u16* __restrict__ src, u16* __restrict__ dst) {
    __shared__ u16 t[64][66];
    const int bh = blockIdx.x >> 5, kt = blockIdx.x & 31;
    const int tid = threadIdx.x;
    const u16* sp = src + ((size_t)bh * 2048 + kt * 64) * 64;
#pragma unroll
    for (int i = 0; i < 2; ++i) {
        int r = (tid >> 3) + i * 32;
        int c0 = (tid & 7) * 8;
        u16x8 v = *(const u16x8*)(sp + (size_t)r * 64 + c0);
#pragma unroll
        for (int j = 0; j < 8; ++j) t[r][c0 + j] = v[j];
    }
    __syncthreads();
    u16* dp = dst + ((size_t)bh * 64) * 2048 + kt * 64;
#pragma unroll
    for (int i = 0; i < 2; ++i) {
        int d = (tid >> 3) + i * 32;
        int k0 = (tid & 7) * 8;
        u16x8 o;
#pragma unroll
        for (int j = 0; j < 8; ++j) o[j] = t[k0 + j][d];
        *(u16x8*)(dp + (size_t)d * 2048 + k0) = o;
    }
}

// ---------------- adjacency -> bitmask (1 bit per entry) ---------------------
__global__ void pack_adj(const float* __restrict__ adj, u64* __restrict__ bits) {
    const int wid = blockIdx.x * 4 + (threadIdx.x >> 6);
    const int lane = threadIdx.x & 63;
    float v = adj[(size_t)wid * 64 + lane];
    u64 mask = __ballot(v > 0.5f);
    if (lane == 0) bits[wid] = mask;
}

// ---------------- LayerNorm over D=512, one wave per row, bf16 out ----------
__global__ void ln_kernel(const float* __restrict__ x, const float* __restrict__ g,
                          const float* __restrict__ b, u16* __restrict__ out) {
    const int w = threadIdx.x >> 6, lane = threadIdx.x & 63;
    const int row = blockIdx.x * 4 + w;
    const float* xr = x + (size_t)row * 512;
    float4 v0 = *(const float4*)(xr + lane * 8);
    float4 v1 = *(const float4*)(xr + lane * 8 + 4);
    float sum = v0.x + v0.y + v0.z + v0.w + v1.x + v1.y + v1.z + v1.w;
    float sq = v0.x * v0.x + v0.y * v0.y + v0.z * v0.z + v0.w * v0.w +
               v1.x * v1.x + v1.y * v1.y + v1.z * v1.z + v1.w * v1.w;
#pragma unroll
    for (int m = 1; m < 64; m <<= 1) {
        sum += __shfl_xor(sum, m);
        sq  += __shfl_xor(sq, m);
    }
    float mu = sum * (1.f / 512.f);
    float var = sq * (1.f / 512.f) - mu * mu;
    float rs = rsqrtf(var + 1e-5f);
    float4 g0 = *(const float4*)(g + lane * 8), g1 = *(const float4*)(g + lane * 8 + 4);
    float4 b0 = *(const float4*)(b + lane * 8), b1 = *(const float4*)(b + lane * 8 + 4);
    u16x8 o;
    o[0] = f2bf((v0.x - mu) * rs * g0.x + b0.x);
    o[1] = f2bf((v0.y - mu) * rs * g0.y + b0.y);
    o[2] = f2bf((v0.z - mu) * rs * g0.z + b0.z);
    o[3] = f2bf((v0.w - mu) * rs * g0.w + b0.w);
    o[4] = f2bf((v1.x - mu) * rs * g1.x + b1.x);
    o[5] = f2bf((v1.y - mu) * rs * g1.y + b1.y);
    o[6] = f2bf((v1.z - mu) * rs * g1.z + b1.z);
    o[7] = f2bf((v1.w - mu) * rs * g1.w + b1.w);
    *(u16x8*)(out + (size_t)row * 512 + lane * 8) = o;
}

// ---------------- bf16 MFMA GEMM, C = A[M,K] @ Bt[N,K]^T, fused epilogues ---
template <int WM, int WN, int EPI, int MINW>
__global__ __launch_bounds__(256, MINW)
void gemm_bt(const u16* __restrict__ A, const u16* __restrict__ Bt,
             int N, int K,
             const float* __restrict__ b0, const float* __restrict__ b1,
             const float* __restrict__ b2, const float* __restrict__ addf,
             float* __restrict__ outf,
             u16* __restrict__ o0, u16* __restrict__ o1, u16* __restrict__ o2) {
    constexpr int BM = 2 * WM, BN = 2 * WN;
    constexpr int MI = WM / 16, NI = WN / 16;
    constexpr int LA = BM / 32, LB = BN / 32;
    __shared__ __align__(16) u16 Als[BM * 64];
    __shared__ __align__(16) u16 Bls[BN * 64];
    const int tid = threadIdx.x, w = tid >> 6, lane = tid & 63;
    // XCD chunk swizzle (all grids %8==0): consecutive same-XCD dispatch ids
    // get contiguous tile ranges -> A-panel reuse within one XCD L2.
    const int bid = ((int)blockIdx.x & 7) * ((int)gridDim.x >> 3) + ((int)blockIdx.x >> 3);
    const int nbn = N / BN;
    const int bm0 = (bid / nbn) * BM;
    const int bn0 = (bid % nbn) * BN;
    const int wr = w >> 1, wc = w & 1;
    const int srow = lane >> 3, schunk = lane & 7;
    f32x4 acc[MI][NI];
#pragma unroll
    for (int i = 0; i < MI; ++i)
#pragma unroll
        for (int j = 0; j < NI; ++j) acc[i][j] = f32x4{0.f, 0.f, 0.f, 0.f};

    for (int k0 = 0; k0 < K; k0 += 64) {
#pragma unroll
        for (int j = 0; j < LA; ++j) {
            int li = w * LA + j;
            int r = li * 8 + srow;
            async16(A + (size_t)(bm0 + r) * K + k0 + ((schunk ^ (r & 7)) << 3), &Als[li * 512]);
        }
#pragma unroll
        for (int j = 0; j < LB; ++j) {
            int li = w * LB + j;
            int r = li * 8 + srow;
            async16(Bt + (size_t)(bn0 + r) * K + k0 + ((schunk ^ (r & 7)) << 3), &Bls[li * 512]);
        }
        __syncthreads();
#pragma unroll
        for (int ks = 0; ks < 2; ++ks) {
            bf16x8 af[MI], bfr[NI];
            const int ck = ks * 4 + (lane >> 4);
#pragma unroll
            for (int mi = 0; mi < MI; ++mi) {
                int r = wr * WM + mi * 16 + (lane & 15);
                af[mi] = *(const bf16x8*)&Als[r * 64 + ((ck ^ (r & 7)) << 3)];
            }
#pragma unroll
            for (int ni = 0; ni < NI; ++ni) {
                int r = wc * WN + ni * 16 + (lane & 15);
                bfr[ni] = *(const bf16x8*)&Bls[r * 64 + ((ck ^ (r & 7)) << 3)];
            }
#pragma unroll
            for (int mi = 0; mi < MI; ++mi)
#pragma unroll
                for (int ni = 0; ni < NI; ++ni)
                    acc[mi][ni] = __builtin_amdgcn_mfma_f32_16x16x32_bf16(
                        af[mi], bfr[ni], acc[mi][ni], 0, 0, 0);
        }
        __syncthreads();
    }
#pragma unroll
    for (int mi = 0; mi < MI; ++mi)
#pragma unroll
        for (int ni = 0; ni < NI; ++ni)
#pragma unroll
            for (int reg = 0; reg < 4; ++reg) {
                int row = bm0 + wr * WM + mi * 16 + ((lane >> 4) << 2) + reg;
                int col = bn0 + wc * WN + ni * 16 + (lane & 15);
                float val = acc[mi][ni][reg];
                if constexpr (EPI == 0) {
                    int wsel = col >> 9, jj = col & 511;
                    const float* bb = wsel == 0 ? b0 : (wsel == 1 ? b1 : b2);
                    u16* dst = wsel == 0 ? o0 : (wsel == 1 ? o1 : o2);
                    val += bb[jj];
                    int h = jj >> 6, hd = jj & 63;
                    int b_ = row >> 11, n_ = row & 2047;
                    dst[(((size_t)(b_ * 8 + h) * 2048 + n_) << 6) + hd] = f2bf(val);
                } else if constexpr (EPI == 1) {
                    val += b0[col] + addf[(size_t)row * 512 + col];
                    outf[(size_t)row * 512 + col] = val;
                } else {
                    float x = val + b0[col];
                    float gx = 0.5f * x * (1.0f + erff(x * 0.70710678118654752f));
                    o0[(size_t)row * 2048 + col] = f2bf(gx);
                }
            }
}

// ---------------- flash attention, swapped-QK^T, split-K over waves ---------
// grid: blockIdx = qt*32 + bh  (bh low bits -> per-bh K/V sticks to one XCD L2)
// block: 4 waves = (qg in {0,1}) x (ks in {0,1}); wave (qg,ks) does q-rows
// [qt*64+qg*32, +32) against keys [ks*1024, +1024). Fixed-M softmax -> O,L are
// pure sums; cross-ks combine is exact addition via LDS at the end.
// V pre-transposed (vT[bh][hd][key]); V AND Q staged via global_load_lds with
// the XOR swizzle folded into the global source address (LDS dest linear).
// Q lives in LDS (not VGPRs): frees 16 persistent regs so the ~100-reg live
// set honestly fits the 128-reg cap of __launch_bounds__(256,4) -> 4 blk/CU.
// LDS = 32KB Vt + 8KB Q = 40KB exactly; 4 x 40KB = 160KB/CU.
__global__ __launch_bounds__(256, 4)
void attn32_kernel(const u16* __restrict__ q, const u16* __restrict__ k,
                   const u16* __restrict__ vT, const u64* __restrict__ adjbits,
                   u16* __restrict__ att) {
    const int tid = threadIdx.x, w = tid >> 6;
    const int lane = tid & 63, col = lane & 31, g = lane >> 5;
    const int qg = w >> 1, ks = w & 1;
    const int bh = blockIdx.x & 31, qt = blockIdx.x >> 5;
    const int b_ = bh >> 3, h_ = bh & 7;
    __shared__ __align__(16) u16 SMEM[20480];  // 40 KB
    u16* Vt = SMEM;                  // [2 ks][2 buf][4096] swizzled V tiles
    u16* Qls = SMEM + 16384;         // [64 q-rows][64 hd] swizzled Q tile
    const int q0 = qt * 64 + qg * 32;
    const int myq = q0 + col;
    const u16* kptr = k + ((size_t)bh * 2048 + ks * 1024 + col) * 64 + g * 8;
    const u64* adjrow = adjbits + ((size_t)b_ * 2048 + myq) * 32 + ks * 16;
    const int sr = lane >> 3, sc = lane & 7;
    const u16* vstage = vT + ((size_t)bh * 64 + qg * 32 + sr) * 2048 + ks * 1024 +
                        ((sc ^ sr) << 3);

    // prologue: stage Q tile (wave w -> rows w*16..+16, pre-swizzled source)
    {
        const u16* qsrc = q + ((size_t)bh * 2048 + qt * 64 + w * 16 + sr) * 64 +
                          ((sc ^ sr) << 3);
        async16(qsrc, Qls + (w * 16) * 64);
        async16(qsrc + 8 * 64, Qls + (w * 16 + 8) * 64);
    }
    f32x16 O0, O1;
#pragma unroll
    for (int i = 0; i < 16; ++i) { O0[i] = 0.f; O1[i] = 0.f; }
    float L = 0.f;

    auto stage = [&](int it, int buf) {
#pragma unroll
        for (int j = 0; j < 4; ++j)
            async16(vstage + (size_t)j * 8 * 2048 + it * 64,
                    Vt + ks * 8192 + buf * 4096 + (qg * 4 + j) * 512);
    };
    stage(0, 0);
    __syncthreads();

    const u16* qbase = Qls + (qg * 32 + col) * 64;
    const int qx = col & 7;
    for (int it = 0; it < 16; ++it) {
        const int cur = it & 1;
        if (it < 15) stage(it + 1, cur ^ 1);
        const u64 adjw = adjrow[it];
        const char* vt = (const char*)(Vt + ks * 8192 + cur * 4096);
        bf16x8 Qf[4];
#pragma unroll
        for (int c = 0; c < 4; ++c)
            Qf[c] = *(const bf16x8*)(qbase + (((c * 2 + g) ^ qx) << 3));
#pragma unroll
        for (int s = 0; s < 2; ++s) {
            bf16x8 Ku[4];
#pragma unroll
            for (int c = 0; c < 4; ++c)
                Ku[c] = *(const bf16x8*)(kptr + (size_t)(it * 64 + s * 32) * 64 + c * 16);
            f32x16 S;
#pragma unroll
            for (int i = 0; i < 16; ++i) S[i] = 0.f;
            __builtin_amdgcn_s_setprio(1);
#pragma unroll
            for (int c = 0; c < 4; ++c)
                S = __builtin_amdgcn_mfma_f32_32x32x16_bf16(Ku[c], Qf[c], S, 0, 0, 0);
            __builtin_amdgcn_s_setprio(0);
            uint32_t w32 = (uint32_t)(adjw >> (32 * s));
            // P = exp2(S*log2e/8 + cst(edge)); fixed offset M=12 (no online max:
            // masked logits bounded; uniform M cancels exactly in O/L)
            float p[16];
#pragma unroll
            for (int r_ = 0; r_ < 16; ++r_) {
                int bit = (r_ & 3) + 8 * (r_ >> 2) + 4 * g;
                float cst = ((w32 >> bit) & 1u) ? -15.8696454f : -20.7550354f;
                p[r_] = __builtin_amdgcn_exp2f(S[r_] * 0.18033688f + cst);
            }
            float t0 = (p[0] + p[1]) + (p[2] + p[3]);
            float t1 = (p[4] + p[5]) + (p[6] + p[7]);
            float t2s = (p[8] + p[9]) + (p[10] + p[11]);
            float t3 = (p[12] + p[13]) + (p[14] + p[15]);
            L += (t0 + t1) + (t2s + t3);
            // pack to bf16 + permlane redistribution -> PV A-fragments
            uint32_t pk[8];
#pragma unroll
            for (int i = 0; i < 8; ++i) {
                union { __bf16 h[2]; uint32_t u; } pu;
                pu.h[0] = (__bf16)p[2 * i]; pu.h[1] = (__bf16)p[2 * i + 1];
                pk[i] = pu.u;
            }
            permswap(pk[0], pk[2]); permswap(pk[1], pk[3]);
            permswap(pk[4], pk[6]); permswap(pk[5], pk[7]);
            union { uint32_t u[4]; bf16x8 v; } fa0, fa1;
            fa0.u[0] = pk[0]; fa0.u[1] = pk[1]; fa0.u[2] = pk[2]; fa0.u[3] = pk[3];
            fa1.u[0] = pk[4]; fa1.u[1] = pk[5]; fa1.u[2] = pk[6]; fa1.u[3] = pk[7];
            __builtin_amdgcn_s_setprio(1);
#pragma unroll
            for (int c2 = 0; c2 < 2; ++c2) {
                int kb = (s * 32 + c2 * 16 + g * 8) * 2;
                int r0 = col, r1 = 32 + col;
                bf16x8 fv0 = *(const bf16x8*)(vt + ((r0 * 128 + kb) ^ ((r0 & 7) << 4)));
                bf16x8 fv1 = *(const bf16x8*)(vt + ((r1 * 128 + kb) ^ ((r1 & 7) << 4)));
                const bf16x8 fa = c2 ? fa1.v : fa0.v;
                O0 = __builtin_amdgcn_mfma_f32_32x32x16_bf16(fa, fv0, O0, 0, 0, 0);
                O1 = __builtin_amdgcn_mfma_f32_32x32x16_bf16(fa, fv1, O1, 0, 0, 0);
            }
            __builtin_amdgcn_s_setprio(0);
        }
        __syncthreads();
    }

    // post-loop: Lls/Obuf overlay the (now dead) Vt region
    float* Obuf = (float*)SMEM;            // [2 qg][32 q][64 hd] = 16 KB
    float* Lls  = (float*)(SMEM + 8192);   // byte 16384: [2 qg][2 ks][32 q]
    float Lt = L + __shfl_xor(L, 32);
    if (g == 0) Lls[(qg * 2 + ks) * 32 + col] = Lt;
    __syncthreads();
    if (ks == 1) {
#pragma unroll
        for (int r_ = 0; r_ < 16; ++r_) {
            int qrow = (r_ & 3) + 8 * (r_ >> 2) + 4 * g;
            Obuf[((qg * 32 + qrow) << 6) + col] = O0[r_];
            Obuf[((qg * 32 + qrow) << 6) + 32 + col] = O1[r_];
        }
    }
    __syncthreads();
    if (ks == 0) {
        u16* outp = att + ((size_t)b_ * 2048 + q0) * 512 + (h_ << 6);
#pragma unroll
        for (int r_ = 0; r_ < 16; ++r_) {
            int qrow = (r_ & 3) + 8 * (r_ >> 2) + 4 * g;
            float lsum = Lls[(qg * 2 + 0) * 32 + qrow] + Lls[(qg * 2 + 1) * 32 + qrow];
            float inv = __builtin_amdgcn_rcpf(lsum);
            float o0 = O0[r_] + Obuf[((qg * 32 + qrow) << 6) + col];
            float o1 = O1[r_] + Obuf[((qg * 32 + qrow) << 6) + 32 + col];
            outp[(size_t)qrow * 512 + col] = f2bf(o0 * inv);
            outp[(size_t)qrow * 512 + 32 + col] = f2bf(o1 * inv);
        }
    }
}

// ---------------------------------------------------------------------------
extern "C" void kernel_launch(void* const* d_in, const int* in_sizes, int n_in,
                              void* d_out, int out_size, void* d_ws, size_t ws_size,
                              hipStream_t stream) {
    const float* hidden = (const float*)d_in[0];
    const float* adj    = (const float*)d_in[1];
    const float* Wq = (const float*)d_in[2];
    const float* bq = (const float*)d_in[3];
    const float* Wk = (const float*)d_in[4];
    const float* bk = (const float*)d_in[5];
    const float* Wv = (const float*)d_in[6];
    const float* bv = (const float*)d_in[7];
    const float* Wo = (const float*)d_in[8];
    const float* bo = (const float*)d_in[9];
    const float* g1 = (const float*)d_in[10];
    const float* b1 = (const float*)d_in[11];
    const float* g2 = (const float*)d_in[12];
    const float* b2 = (const float*)d_in[13];
    const float* Wf1 = (const float*)d_in[14];
    const float* bf1 = (const float*)d_in[15];
    const float* Wf2 = (const float*)d_in[16];
    const float* bf2 = (const float*)d_in[17];
    float* out = (float*)d_out;

    char* p = (char*)d_ws;
    u16* wqkv_t = (u16*)p; p += (size_t)1536 * 512 * 2;
    u16* wo_t   = (u16*)p; p += (size_t)512 * 512 * 2;
    u16* wf1_t  = (u16*)p; p += (size_t)2048 * 512 * 2;
    u16* wf2_t  = (u16*)p; p += (size_t)512 * 2048 * 2;
    u64* adjbits = (u64*)p; p += (size_t)4 * 2048 * 32 * 8;
    u16* bufA = (u16*)p; p += (size_t)8192 * 512 * 2;   // normed, then attended
    u16* bufQ = (u16*)p; p += (size_t)8192 * 512 * 2;   // q, then h2
    float* mid = (float*)p; p += (size_t)8192 * 512 * 4;
    u16* kbuf = (u16*)p; p += (size_t)8192 * 512 * 2;
    u16* vbuf = (u16*)p; p += (size_t)8192 * 512 * 2;
    p += (size_t)16 * 1024 * 1024;                       // ffh tail
    u16* ffh = kbuf;  // 8192*2048 bf16 spans kbuf+vbuf+tail (dead after attention)
    u16* vT = (u16*)mid;  // [32 bh][64 hd][2048 key] bf16; mid dead until Wo-GEMM
    (void)ws_size; (void)in_sizes; (void)n_in; (void)out_size;

    transpose_w<<<64, 256, 0, stream>>>(Wq, wqkv_t, 512, 512);
    transpose_w<<<64, 256, 0, stream>>>(Wk, wqkv_t + (size_t)512 * 512, 512, 512);
    transpose_w<<<64, 256, 0, stream>>>(Wv, wqkv_t + (size_t)1024 * 512, 512, 512);
    transpose_w<<<64, 256, 0, stream>>>(Wo, wo_t, 512, 512);
    transpose_w<<<256, 256, 0, stream>>>(Wf1, wf1_t, 512, 2048);
    transpose_w<<<256, 256, 0, stream>>>(Wf2, wf2_t, 2048, 512);
    pack_adj<<<65536, 256, 0, stream>>>(adj, adjbits);
    ln_kernel<<<2048, 256, 0, stream>>>(hidden, g1, b1, bufA);
    gemm_bt<64, 64, 0, 3><<<64 * 12, 256, 0, stream>>>(bufA, wqkv_t, 1536, 512,
        bq, bk, bv, nullptr, nullptr, bufQ, kbuf, vbuf);
    transpose_v<<<1024, 256, 0, stream>>>(vbuf, vT);
    attn32_kernel<<<1024, 256, 0, stream>>>(bufQ, kbuf, vT, adjbits, bufA);
    gemm_bt<32, 64, 1, 4><<<512, 256, 0, stream>>>(bufA, wo_t, 512, 512,
        bo, nullptr, nullptr, hidden, mid, nullptr, nullptr, nullptr);
    ln_kernel<<<2048, 256, 0, stream>>>(mid, g2, b2, bufQ);
    gemm_bt<64, 64, 2, 3><<<64 * 16, 256, 0, stream>>>(bufQ, wf1_t, 2048, 512,
        bf1, nullptr, nullptr, nullptr, nullptr, ffh, nullptr, nullptr);
    gemm_bt<32, 64, 1, 4><<<512, 256, 0, stream>>>(ffh, wf2_t, 512, 2048,
        bf2, nullptr, nullptr, mid, out, nullptr, nullptr, nullptr);
}